// Round 2
// baseline (587.817 us; speedup 1.0000x reference)
//
#include <hip/hip_runtime.h>

// ---------------------------------------------------------------------------
// MMoE: B=8192, D_IN=1024, E=8, T=4, H1=1024, H2=512, H3=256
// R9: R8's 256x256 8-phase schedule, FIXED:
//   - fragment loads are inline-asm ds_read_b128 (as(3) addr). R8 used
//     compiler loads; the compiler could not disambiguate them from the
//     outstanding global_load_lds LDS-writes and inserted s_waitcnt vmcnt(0)
//     before EVERY phase's ds_reads -> pipeline degenerated to a
//     sync-every-phase loop (~900 cyc/phase, MfmaUtil 29%). asm reads keep
//     LDS reads out of the compiler's memory-dependence graph; the only
//     vmcnt waits in the main loop are the counted vmcnt(4) checkpoints.
//   - rule #18 fence: after each phase's first barrier, explicit
//     s_waitcnt lgkmcnt(0) + sched_barrier(0) so MFMAs can't hoist above.
//   - epilogue reordered row-outer so each wave writes its full 128B line
//     per row in one burst (R8 WRITE_SIZE was 2x C from partial-line
//     evictions).
// Schedule (verified correct in R8): 4 phases/K-tile, quadrants
// Q(0,0),Q(0,1),Q(1,1),Q(1,0); PF1 p1/p2 finishes tile t+1 into nxt buf;
// PF2 p3/p4 starts tile t+2 into cur buf (regions whose reads finished a
// phase earlier); one vmcnt(4) per K-tile, never 0 in the main loop.
// XCD-ownership block swizzle kept: e = lin&7 owns the expert, n fastest.
// ---------------------------------------------------------------------------

#define B_ROWS 8192
#define D_IN   1024
#define NEXP   8
#define NTASK  4
#define H1     1024
#define H2     512
#define H3     256

typedef __attribute__((ext_vector_type(8))) short bf16x8;
typedef __attribute__((ext_vector_type(4))) float f32x4;
typedef __attribute__((ext_vector_type(4))) int   i32x4;

__device__ __forceinline__ unsigned short f2bf(float f) {
    union { float f; unsigned int u; } x; x.f = f;
    unsigned int r = x.u + 0x7fffu + ((x.u >> 16) & 1u);  // RNE
    return (unsigned short)(r >> 16);
}
__device__ __forceinline__ float bf2f(unsigned short u) {
    union { unsigned int u; float f; } x; x.u = ((unsigned int)u) << 16;
    return x.f;
}

__device__ __forceinline__ void gload_lds16(const void* gptr, void* lptr) {
    __builtin_amdgcn_global_load_lds(
        (__attribute__((address_space(1))) void*)gptr,
        (__attribute__((address_space(3))) void*)lptr,
        16, 0, 0);
}

// inline-asm LDS read: invisible to compiler vmcnt tracking (the fix).
__device__ __forceinline__ bf16x8 ldsr(const unsigned short* p) {
    i32x4 r;
    asm volatile("ds_read_b128 %0, %1"
                 : "=v"(r)
                 : "v"((__attribute__((address_space(3))) const unsigned short*)p));
    return __builtin_bit_cast(bf16x8, r);
}

struct __align__(8) us4 { unsigned short x, y, z, w; };

// raw barrier with compiler memory fences (no implicit vmcnt(0) drain)
#define BAR() do {                                   \
        asm volatile("" ::: "memory");               \
        __builtin_amdgcn_s_barrier();                \
        asm volatile("" ::: "memory");               \
    } while (0)

// rule #18: wait ds_reads, then pin so MFMAs can't hoist above the wait
#define LGKM0() do {                                         \
        asm volatile("s_waitcnt lgkmcnt(0)" ::: "memory");   \
        __builtin_amdgcn_sched_barrier(0);                   \
    } while (0)

#define MFMA_BF16(a, b, c) \
    __builtin_amdgcn_mfma_f32_16x16x32_bf16((a), (b), (c), 0, 0, 0)

// ---------------------------------------------------------------------------
// W [E][K][N] fp32 -> Wt [E][N][K] bf16. 64x64 tiles, block 256.
// ---------------------------------------------------------------------------
__global__ void transpose_convert_kernel(const float* __restrict__ W,
                                         unsigned short* __restrict__ Wt,
                                         int K, int N) {
    __shared__ float tile[64][65];
    const int e = blockIdx.z;
    const float* We = W + (size_t)e * K * N;
    unsigned short* Wte = Wt + (size_t)e * K * N;
    const int k0 = blockIdx.x * 64, n0 = blockIdx.y * 64;
    const int tid = threadIdx.x;
    const int tn = tid & 63;
    const int tk = tid >> 6;
#pragma unroll
    for (int i = 0; i < 16; ++i)
        tile[tk * 16 + i][tn] = We[(size_t)(k0 + tk * 16 + i) * N + n0 + tn];
    __syncthreads();
    const int wk = (tid & 15) * 4;
    const int wn = tid >> 4;
#pragma unroll
    for (int i = 0; i < 4; ++i) {
        const int n = wn + i * 16;
        us4 o;
        o.x = f2bf(tile[wk + 0][n]);
        o.y = f2bf(tile[wk + 1][n]);
        o.z = f2bf(tile[wk + 2][n]);
        o.w = f2bf(tile[wk + 3][n]);
        *(us4*)&Wte[(size_t)(n0 + n) * K + k0 + wk] = o;
    }
}

// ---------------------------------------------------------------------------
// 8-phase GEMM helpers
// ---------------------------------------------------------------------------

// stage one 128-row half-tile (2 x global_load_lds dwordx4 per thread).
__device__ __forceinline__ void stage_half(const unsigned short* g,
                                           unsigned short* s,
                                           int h, int kt, int K, int tid) {
    gload_lds16(g + (size_t)(h * 128) * K + kt * 64,
                s + h * 8192 + tid * 8);
    gload_lds16(g + (size_t)(h * 128 + 64) * K + kt * 64,
                s + h * 8192 + 4096 + tid * 8);
}

// One K-tile = 4 phases. cur buf = sAc/sBc, other buf = sAn/sBn.
// PF1: stage tile kt1 halves {B1,A1} into nxt (p1,p2).
// PF2: stage tile kt2 halves {B0,A0} into cur (p3,p4).
// CKPT: 4 -> vmcnt(4) at p4; 0 -> vmcnt(0); -1 -> none (last tile).
template <bool PF1, bool PF2, int CKPT>
__device__ __forceinline__ void tile8(
    unsigned short* sAc, unsigned short* sBc,
    unsigned short* sAn, unsigned short* sBn,
    const unsigned short* gA, const unsigned short* gB,
    int K, int tid, int aRow, int bRow, int ck0, int ck1,
    int kt1, int kt2, f32x4 (&acc)[8][4]) {
    bf16x8 af[4][2], b0[2][2], b1[2][2];

    // ---- phase 1: Q(0,0) -- read A[ih=0] (8) + B[jh=0] (4); stage kt1.B1
#pragma unroll
    for (int i = 0; i < 4; ++i) {
        af[i][0] = ldsr(&sAc[aRow + i * 16 * 64 + ck0]);
        af[i][1] = ldsr(&sAc[aRow + i * 16 * 64 + ck1]);
    }
#pragma unroll
    for (int j = 0; j < 2; ++j) {
        b0[j][0] = ldsr(&sBc[bRow + j * 16 * 64 + ck0]);
        b0[j][1] = ldsr(&sBc[bRow + j * 16 * 64 + ck1]);
    }
    if (PF1) stage_half(gB, sBn, 1, kt1, K, tid);
    BAR();
    LGKM0();
    __builtin_amdgcn_s_setprio(1);
#pragma unroll
    for (int i = 0; i < 4; ++i)
#pragma unroll
        for (int j = 0; j < 2; ++j) {
            acc[i][j] = MFMA_BF16(af[i][0], b0[j][0], acc[i][j]);
            acc[i][j] = MFMA_BF16(af[i][1], b0[j][1], acc[i][j]);
        }
    __builtin_amdgcn_s_setprio(0);
    BAR();

    // ---- phase 2: Q(0,1) -- read B[jh=1] (4); stage kt1.A1
#pragma unroll
    for (int j = 0; j < 2; ++j) {
        b1[j][0] = ldsr(&sBc[bRow + (32 + j * 16) * 64 + ck0]);
        b1[j][1] = ldsr(&sBc[bRow + (32 + j * 16) * 64 + ck1]);
    }
    if (PF1) stage_half(gA, sAn, 1, kt1, K, tid);
    BAR();
    LGKM0();
    __builtin_amdgcn_s_setprio(1);
#pragma unroll
    for (int i = 0; i < 4; ++i)
#pragma unroll
        for (int j = 0; j < 2; ++j) {
            acc[i][2 + j] = MFMA_BF16(af[i][0], b1[j][0], acc[i][2 + j]);
            acc[i][2 + j] = MFMA_BF16(af[i][1], b1[j][1], acc[i][2 + j]);
        }
    __builtin_amdgcn_s_setprio(0);
    BAR();

    // ---- phase 3: Q(1,1) -- read A[ih=1] (8); stage kt2.B0 into cur
    //      (all B reads of cur finished in p2 -> write-after-read safe)
#pragma unroll
    for (int i = 0; i < 4; ++i) {
        af[i][0] = ldsr(&sAc[aRow + (64 + i * 16) * 64 + ck0]);
        af[i][1] = ldsr(&sAc[aRow + (64 + i * 16) * 64 + ck1]);
    }
    if (PF2) stage_half(gB, sBc, 0, kt2, K, tid);
    BAR();
    LGKM0();
    __builtin_amdgcn_s_setprio(1);
#pragma unroll
    for (int i = 0; i < 4; ++i)
#pragma unroll
        for (int j = 0; j < 2; ++j) {
            acc[4 + i][2 + j] = MFMA_BF16(af[i][0], b1[j][0], acc[4 + i][2 + j]);
            acc[4 + i][2 + j] = MFMA_BF16(af[i][1], b1[j][1], acc[4 + i][2 + j]);
        }
    __builtin_amdgcn_s_setprio(0);
    BAR();

    // ---- phase 4: Q(1,0) -- no reads (b0/af regs live); stage kt2.A0
    //      (all A reads of cur finished in p3); counted-vmcnt checkpoint
    if (PF2) stage_half(gA, sAc, 0, kt2, K, tid);
    BAR();
    __builtin_amdgcn_s_setprio(1);
#pragma unroll
    for (int i = 0; i < 4; ++i)
#pragma unroll
        for (int j = 0; j < 2; ++j) {
            acc[4 + i][j] = MFMA_BF16(af[i][0], b0[j][0], acc[4 + i][j]);
            acc[4 + i][j] = MFMA_BF16(af[i][1], b0[j][1], acc[4 + i][j]);
        }
    __builtin_amdgcn_s_setprio(0);
    if (CKPT == 4)      asm volatile("s_waitcnt vmcnt(4)" ::: "memory");
    else if (CKPT == 0) asm volatile("s_waitcnt vmcnt(0)" ::: "memory");
    BAR();
}

// ---------------------------------------------------------------------------
// GEMM: C[e] = relu(A[e] @ Bt[e]^T + bias[e]) ; bf16 in, fp32 acc, bf16 out
// A: [M,K] rm, Bt: [N,K] rm, C: [M,N] rm. tile 256x256, BK=64, NT = K/64
// (even, >=4 for all layers). grid = (M/256, N/256, 8), all pow2, total%8==0.
// ---------------------------------------------------------------------------
__global__ __launch_bounds__(512, 2) void gemm256_bias_relu_kernel(
    const unsigned short* __restrict__ A, long long Aes,
    const unsigned short* __restrict__ Bt, long long Bes,
    const float* __restrict__ bias, long long bias_es,
    unsigned short* __restrict__ C, long long Ces,
    int M, int N, int K) {
    __shared__ __align__(16) unsigned short sA[2][16384];  // [buf][256*64]
    __shared__ __align__(16) unsigned short sB[2][16384];

    const int tid  = threadIdx.x;
    const int lane = tid & 63;
    const int w    = tid >> 6;        // wave 0..7
    const int wm   = w >> 2;          // 0..1  (M half)
    const int wn   = w & 3;           // 0..3  (N quarter)
    const int quad = lane >> 4, l15 = lane & 15;
    const int swz  = l15 & 7;
    const int srow = tid >> 3;        // staging row 0..63
    const int schk = tid & 7;         // staging 16B chunk
    const int gchunk = schk ^ (srow & 7);   // source pre-swizzle

    // XCD-ownership block swizzle (lin%8 -> XCD heuristic)
    const unsigned int gy   = gridDim.y;
    const unsigned int lin  = blockIdx.x + gridDim.x * (blockIdx.y + gy * blockIdx.z);
    const unsigned int e    = lin & 7;
    const unsigned int slot = lin >> 3;
    const int gysh = __builtin_ctz(gy);
    const int n0 = (int)(slot & (gy - 1)) * 256;   // n fastest within XCD
    const int m0 = (int)(slot >> gysh) * 256;

    A    += (size_t)e * Aes;
    Bt   += (size_t)e * Bes;
    bias += (size_t)e * bias_es;
    C    += (size_t)e * Ces;

    const unsigned short* gA = A  + (size_t)(m0 + srow) * K + gchunk * 8;
    const unsigned short* gB = Bt + (size_t)(n0 + srow) * K + gchunk * 8;

    f32x4 acc[8][4] = {};

    // prologue: T0 {B0,A0,B1,A1} -> buf0 ; T1 {B0,A0} -> buf1 ; vmcnt(4)
    stage_half(gB, sB[0], 0, 0, K, tid);
    stage_half(gA, sA[0], 0, 0, K, tid);
    stage_half(gB, sB[0], 1, 0, K, tid);
    stage_half(gA, sA[0], 1, 0, K, tid);
    stage_half(gB, sB[1], 0, 1, K, tid);
    stage_half(gA, sA[1], 0, 1, K, tid);
    asm volatile("s_waitcnt vmcnt(4)" ::: "memory");
    BAR();

    const int aRow = (wm * 128 + l15) * 64;
    const int bRow = (wn * 64 + l15) * 64;
    const int ck0  = ((0 + quad) ^ swz) * 8;    // k-slice 0 chunk (swizzled)
    const int ck1  = ((4 + quad) ^ swz) * 8;    // k-slice 1 chunk
    const int NT   = K >> 6;

    int t = 0;
    for (; t + 3 < NT; t += 2) {
        tile8<true, true, 4>(sA[0], sB[0], sA[1], sB[1], gA, gB, K, tid,
                             aRow, bRow, ck0, ck1, t + 1, t + 2, acc);
        tile8<true, true, 4>(sA[1], sB[1], sA[0], sB[0], gA, gB, K, tid,
                             aRow, bRow, ck0, ck1, t + 2, t + 3, acc);
    }
    // t == NT-2: finish staging T(NT-1), drain, then last tile w/o prefetch
    tile8<true, false, 0>(sA[0], sB[0], sA[1], sB[1], gA, gB, K, tid,
                          aRow, bRow, ck0, ck1, NT - 1, 0, acc);
    tile8<false, false, -1>(sA[1], sB[1], sA[0], sB[0], gA, gB, K, tid,
                            aRow, bRow, ck0, ck1, 0, 0, acc);

    // epilogue: C/D layout col=lane&15, row=quad*4+reg.
    // row-outer / j-inner: each wave writes its full 128B line per row in
    // one burst (R8's j-outer order caused 2x write amplification).
    float bv[4];
#pragma unroll
    for (int j = 0; j < 4; ++j) bv[j] = bias[n0 + wn * 64 + j * 16 + l15];
#pragma unroll
    for (int i = 0; i < 8; ++i) {
#pragma unroll
        for (int r = 0; r < 4; ++r) {
            const int row = m0 + wm * 128 + i * 16 + quad * 4 + r;
            unsigned short* Crow = &C[(size_t)row * N + n0 + wn * 64 + l15];
#pragma unroll
            for (int j = 0; j < 4; ++j) {
                float v = acc[i][j][r] + bv[j];
                v = v > 0.f ? v : 0.f;
                Crow[j * 16] = f2bf(v);
            }
        }
    }
}

// ---------------------------------------------------------------------------
// gates + x->bf16 convert fused. block 256 = 8 rows x 32 outputs.
// ---------------------------------------------------------------------------
__global__ void gates_convert_kernel(const float* __restrict__ x,
                                     const float* __restrict__ gw,
                                     float* __restrict__ gates,
                                     unsigned short* __restrict__ xb) {
    const int tid = threadIdx.x;
    const size_t base = (size_t)blockIdx.x * 8192 + (size_t)tid * 32;
#pragma unroll
    for (int i = 0; i < 8; ++i) {
        float4 v = *(const float4*)&x[base + i * 4];
        us4 o4;
        o4.x = f2bf(v.x); o4.y = f2bf(v.y); o4.z = f2bf(v.z); o4.w = f2bf(v.w);
        ((us4*)xb)[base / 4 + i] = o4;
    }
    const int o = tid & 31;          // t*8 + e
    const int r = tid >> 5;          // 0..7
    const int b = blockIdx.x * 8 + r;
    const float* xr = x + (size_t)b * D_IN;
    float acc = 0.f;
    for (int k = 0; k < D_IN; k += 4) {
        float4 xv = *(const float4*)&xr[k];
        acc += xv.x * gw[(k + 0) * 32 + o];
        acc += xv.y * gw[(k + 1) * 32 + o];
        acc += xv.z * gw[(k + 2) * 32 + o];
        acc += xv.w * gw[(k + 3) * 32 + o];
    }
    float m = acc;
    m = fmaxf(m, __shfl_xor(m, 1));
    m = fmaxf(m, __shfl_xor(m, 2));
    m = fmaxf(m, __shfl_xor(m, 4));
    float ex = __expf(acc - m);
    float s = ex;
    s += __shfl_xor(s, 1);
    s += __shfl_xor(s, 2);
    s += __shfl_xor(s, 4);
    gates[(size_t)b * 32 + o] = ex / s;
}

// ---------------------------------------------------------------------------
// combine: out[t][b][d] = sum_e h3[e][b][d] * g[b][t*8+e]
// ---------------------------------------------------------------------------
__global__ void combine_kernel(const unsigned short* __restrict__ h3,
                               const float* __restrict__ gates,
                               float* __restrict__ out) {
    __shared__ float g[32];
    const int b = blockIdx.x;
    const int d = threadIdx.x;
    if (d < 32) g[d] = gates[(size_t)b * 32 + d];
    __syncthreads();
    float acc[NTASK] = {0.f, 0.f, 0.f, 0.f};
#pragma unroll
    for (int e = 0; e < NEXP; ++e) {
        const float h = bf2f(h3[((size_t)e * B_ROWS + b) * H3 + d]);
#pragma unroll
        for (int t = 0; t < NTASK; ++t) acc[t] += h * g[t * 8 + e];
    }
#pragma unroll
    for (int t = 0; t < NTASK; ++t)
        out[((size_t)t * B_ROWS + b) * H3 + d] = acc[t];
}

// ---------------------------------------------------------------------------
// workspace layout (bytes)
// ---------------------------------------------------------------------------
#define OFF_XBF 0u                          // 8192*1024*2      = 16,777,216
#define OFF_W1T 16777216u                   // 8*1024*1024*2    = 16,777,216
#define OFF_W2T 33554432u                   // 8*512*1024*2     =  8,388,608
#define OFF_W3T 41943040u                   // 8*256*512*2      =  2,097,152
#define OFF_G   44040192u                   // 8192*32*4        =  1,048,576
#define OFF_H1  45088768u                   // 8*8192*1024*2    = 134,217,728
#define OFF_H2  179306496u                  // 8*8192*512*2     = 67,108,864
#define OFF_H3  45088768u                   // aliases h1 (h1 dead after L2)
// total required: 246,415,360 bytes

extern "C" void kernel_launch(void* const* d_in, const int* in_sizes, int n_in,
                              void* d_out, int out_size, void* d_ws, size_t ws_size,
                              hipStream_t stream) {
    const float* x  = (const float*)d_in[0];
    const float* W1 = (const float*)d_in[1];
    const float* b1 = (const float*)d_in[2];
    const float* W2 = (const float*)d_in[3];
    const float* b2 = (const float*)d_in[4];
    const float* W3 = (const float*)d_in[5];
    const float* b3 = (const float*)d_in[6];
    const float* gw = (const float*)d_in[7];
    float* out = (float*)d_out;
    char* ws = (char*)d_ws;

    unsigned short* xbf = (unsigned short*)(ws + OFF_XBF);
    unsigned short* w1t = (unsigned short*)(ws + OFF_W1T);
    unsigned short* w2t = (unsigned short*)(ws + OFF_W2T);
    unsigned short* w3t = (unsigned short*)(ws + OFF_W3T);
    float*          gts = (float*)(ws + OFF_G);
    unsigned short* h1  = (unsigned short*)(ws + OFF_H1);
    unsigned short* h2  = (unsigned short*)(ws + OFF_H2);
    unsigned short* h3  = (unsigned short*)(ws + OFF_H3);

    // weight transposes + fused gates/x-convert
    transpose_convert_kernel<<<dim3(D_IN / 64, H1 / 64, NEXP), dim3(256), 0, stream>>>(W1, w1t, D_IN, H1);
    transpose_convert_kernel<<<dim3(H1 / 64, H2 / 64, NEXP), dim3(256), 0, stream>>>(W2, w2t, H1, H2);
    transpose_convert_kernel<<<dim3(H2 / 64, H3 / 64, NEXP), dim3(256), 0, stream>>>(W3, w3t, H2, H3);
    gates_convert_kernel<<<dim3(B_ROWS / 8), dim3(256), 0, stream>>>(x, gw, gts, xbf);

    // expert MLP layers (256x256 8-phase GEMM)
    gemm256_bias_relu_kernel<<<dim3(B_ROWS / 256, H1 / 256, NEXP), dim3(512), 0, stream>>>(
        xbf, 0LL,
        w1t, (long long)H1 * D_IN,
        b1, (long long)H1,
        h1, (long long)B_ROWS * H1,
        B_ROWS, H1, D_IN);
    gemm256_bias_relu_kernel<<<dim3(B_ROWS / 256, H2 / 256, NEXP), dim3(512), 0, stream>>>(
        h1, (long long)B_ROWS * H1,
        w2t, (long long)H2 * H1,
        b2, (long long)H2,
        h2, (long long)B_ROWS * H2,
        B_ROWS, H2, H1);
    gemm256_bias_relu_kernel<<<dim3(B_ROWS / 256, H3 / 256, NEXP), dim3(512), 0, stream>>>(
        h2, (long long)B_ROWS * H2,
        w3t, (long long)H3 * H2,
        b3, (long long)H3,
        h3, (long long)B_ROWS * H3,
        B_ROWS, H3, H2);

    // gated combine
    combine_kernel<<<dim3(B_ROWS), dim3(256), 0, stream>>>(h3, gts, out);
}

// Round 4
// 563.517 us; speedup vs baseline: 1.0431x; 1.0431x over previous
//
#include <hip/hip_runtime.h>

// ---------------------------------------------------------------------------
// MMoE: B=8192, D_IN=1024, E=8, T=4, H1=1024, H2=512, H3=256
// R11 = R10 resubmitted verbatim (round-3 bench died in infra before the
// kernel ever ran: "container failed twice", no pytest/profile output).
// R10: R9's 256x256 4-phase/K-tile schedule with the REAL drain leak fixed.
//   R8/R9 post-mortem: any inline asm with a ":::memory" clobber is treated
//   by SIInsertWaitcnts as a may-load/may-store instruction it cannot
//   disambiguate from in-flight global_load_lds LDS-writes -> it inserts
//   s_waitcnt vmcnt(0) before EVERY such asm. BAR()'s fence wrappers +
//   clobbered waitcnt asm put 10+ of these per K-tile -> every phase paid a
//   full load-latency stall (MfmaUtil 25-29%, ~8700 cyc/K-tile vs ~3500
//   template). Fix (faithful to the verified m201 template):
//     - bare __builtin_amdgcn_s_barrier() (no fence wrappers)
//     - clobber-free asm volatile("s_waitcnt lgkmcnt(0)") + sched_barrier(0)
//       (rule #18) before each MFMA cluster
//     - clobber-free counted vmcnt(4), once per K-tile, never 0 in-loop
//   Ordering safety without clobbers: staging intrinsics, volatile-asm
//   ds_reads, and barriers are all side-effecting -> mutually ordered;
//   MFMAs pinned by ds_read data deps + sched_barrier(0); C-stores pinned
//   by acc data deps.
// Schedule (correctness verified in R8/R9): 4 phases/K-tile, quadrants
// Q(0,0),Q(0,1),Q(1,1),Q(1,0); p1/p2 finish tile t+1 into nxt buf; p3/p4
// start tile t+2 into cur buf (regions whose reads finished a phase
// earlier); prologue depth 12 loads, vmcnt(4) checkpoint per tile.
// XCD-ownership block swizzle kept: e = lin&7 owns the expert, n fastest.
// ---------------------------------------------------------------------------

#define B_ROWS 8192
#define D_IN   1024
#define NEXP   8
#define NTASK  4
#define H1     1024
#define H2     512
#define H3     256

typedef __attribute__((ext_vector_type(8))) short bf16x8;
typedef __attribute__((ext_vector_type(4))) float f32x4;
typedef __attribute__((ext_vector_type(4))) int   i32x4;

__device__ __forceinline__ unsigned short f2bf(float f) {
    union { float f; unsigned int u; } x; x.f = f;
    unsigned int r = x.u + 0x7fffu + ((x.u >> 16) & 1u);  // RNE
    return (unsigned short)(r >> 16);
}
__device__ __forceinline__ float bf2f(unsigned short u) {
    union { unsigned int u; float f; } x; x.u = ((unsigned int)u) << 16;
    return x.f;
}

__device__ __forceinline__ void gload_lds16(const void* gptr, void* lptr) {
    __builtin_amdgcn_global_load_lds(
        (__attribute__((address_space(1))) void*)gptr,
        (__attribute__((address_space(3))) void*)lptr,
        16, 0, 0);
}

// inline-asm LDS read: invisible to compiler vmcnt tracking. NO clobbers.
__device__ __forceinline__ bf16x8 ldsr(const unsigned short* p) {
    i32x4 r;
    asm volatile("ds_read_b128 %0, %1"
                 : "=v"(r)
                 : "v"((__attribute__((address_space(3))) const unsigned short*)p));
    return __builtin_bit_cast(bf16x8, r);
}

struct __align__(8) us4 { unsigned short x, y, z, w; };

// bare barrier: no fence wrappers -> no compiler-inserted vmcnt(0) drain
#define BARRIER() __builtin_amdgcn_s_barrier()

// rule #18: clobber-free lgkm wait + sched fence so MFMAs can't hoist above
#define WAIT_LGKM0() do {                                \
        asm volatile("s_waitcnt lgkmcnt(0)");            \
        __builtin_amdgcn_sched_barrier(0);               \
    } while (0)

#define MFMA_BF16(a, b, c) \
    __builtin_amdgcn_mfma_f32_16x16x32_bf16((a), (b), (c), 0, 0, 0)

// ---------------------------------------------------------------------------
// W [E][K][N] fp32 -> Wt [E][N][K] bf16. 64x64 tiles, block 256.
// ---------------------------------------------------------------------------
__global__ void transpose_convert_kernel(const float* __restrict__ W,
                                         unsigned short* __restrict__ Wt,
                                         int K, int N) {
    __shared__ float tile[64][65];
    const int e = blockIdx.z;
    const float* We = W + (size_t)e * K * N;
    unsigned short* Wte = Wt + (size_t)e * K * N;
    const int k0 = blockIdx.x * 64, n0 = blockIdx.y * 64;
    const int tid = threadIdx.x;
    const int tn = tid & 63;
    const int tk = tid >> 6;
#pragma unroll
    for (int i = 0; i < 16; ++i)
        tile[tk * 16 + i][tn] = We[(size_t)(k0 + tk * 16 + i) * N + n0 + tn];
    __syncthreads();
    const int wk = (tid & 15) * 4;
    const int wn = tid >> 4;
#pragma unroll
    for (int i = 0; i < 4; ++i) {
        const int n = wn + i * 16;
        us4 o;
        o.x = f2bf(tile[wk + 0][n]);
        o.y = f2bf(tile[wk + 1][n]);
        o.z = f2bf(tile[wk + 2][n]);
        o.w = f2bf(tile[wk + 3][n]);
        *(us4*)&Wte[(size_t)(n0 + n) * K + k0 + wk] = o;
    }
}

// ---------------------------------------------------------------------------
// 8-phase GEMM helpers
// ---------------------------------------------------------------------------

// stage one 128-row half-tile (2 x global_load_lds dwordx4 per thread).
__device__ __forceinline__ void stage_half(const unsigned short* g,
                                           unsigned short* s,
                                           int h, int kt, int K, int tid) {
    gload_lds16(g + (size_t)(h * 128) * K + kt * 64,
                s + h * 8192 + tid * 8);
    gload_lds16(g + (size_t)(h * 128 + 64) * K + kt * 64,
                s + h * 8192 + 4096 + tid * 8);
}

// One K-tile = 4 phases. cur buf = sAc/sBc, other buf = sAn/sBn.
// PF1: stage tile kt1 halves {B1,A1} into nxt (p1,p2).
// PF2: stage tile kt2 halves {B0,A0} into cur (p3,p4).
// CKPT: 4 -> vmcnt(4) at p4; 0 -> vmcnt(0); -1 -> none (last tile).
template <bool PF1, bool PF2, int CKPT>
__device__ __forceinline__ void tile8(
    unsigned short* sAc, unsigned short* sBc,
    unsigned short* sAn, unsigned short* sBn,
    const unsigned short* gA, const unsigned short* gB,
    int K, int tid, int aRow, int bRow, int ck0, int ck1,
    int kt1, int kt2, f32x4 (&acc)[8][4]) {
    bf16x8 af[4][2], b0[2][2], b1[2][2];

    // ---- phase 1: Q(0,0) -- read A[ih=0] (8) + B[jh=0] (4); stage kt1.B1
#pragma unroll
    for (int i = 0; i < 4; ++i) {
        af[i][0] = ldsr(&sAc[aRow + i * 16 * 64 + ck0]);
        af[i][1] = ldsr(&sAc[aRow + i * 16 * 64 + ck1]);
    }
#pragma unroll
    for (int j = 0; j < 2; ++j) {
        b0[j][0] = ldsr(&sBc[bRow + j * 16 * 64 + ck0]);
        b0[j][1] = ldsr(&sBc[bRow + j * 16 * 64 + ck1]);
    }
    if (PF1) stage_half(gB, sBn, 1, kt1, K, tid);
    BARRIER();
    WAIT_LGKM0();
    __builtin_amdgcn_s_setprio(1);
#pragma unroll
    for (int i = 0; i < 4; ++i)
#pragma unroll
        for (int j = 0; j < 2; ++j) {
            acc[i][j] = MFMA_BF16(af[i][0], b0[j][0], acc[i][j]);
            acc[i][j] = MFMA_BF16(af[i][1], b0[j][1], acc[i][j]);
        }
    __builtin_amdgcn_s_setprio(0);
    BARRIER();

    // ---- phase 2: Q(0,1) -- read B[jh=1] (4); stage kt1.A1
#pragma unroll
    for (int j = 0; j < 2; ++j) {
        b1[j][0] = ldsr(&sBc[bRow + (32 + j * 16) * 64 + ck0]);
        b1[j][1] = ldsr(&sBc[bRow + (32 + j * 16) * 64 + ck1]);
    }
    if (PF1) stage_half(gA, sAn, 1, kt1, K, tid);
    BARRIER();
    WAIT_LGKM0();
    __builtin_amdgcn_s_setprio(1);
#pragma unroll
    for (int i = 0; i < 4; ++i)
#pragma unroll
        for (int j = 0; j < 2; ++j) {
            acc[i][2 + j] = MFMA_BF16(af[i][0], b1[j][0], acc[i][2 + j]);
            acc[i][2 + j] = MFMA_BF16(af[i][1], b1[j][1], acc[i][2 + j]);
        }
    __builtin_amdgcn_s_setprio(0);
    BARRIER();

    // ---- phase 3: Q(1,1) -- read A[ih=1] (8); stage kt2.B0 into cur
    //      (all B reads of cur finished in p2 -> write-after-read safe)
#pragma unroll
    for (int i = 0; i < 4; ++i) {
        af[i][0] = ldsr(&sAc[aRow + (64 + i * 16) * 64 + ck0]);
        af[i][1] = ldsr(&sAc[aRow + (64 + i * 16) * 64 + ck1]);
    }
    if (PF2) stage_half(gB, sBc, 0, kt2, K, tid);
    BARRIER();
    WAIT_LGKM0();
    __builtin_amdgcn_s_setprio(1);
#pragma unroll
    for (int i = 0; i < 4; ++i)
#pragma unroll
        for (int j = 0; j < 2; ++j) {
            acc[4 + i][2 + j] = MFMA_BF16(af[i][0], b1[j][0], acc[4 + i][2 + j]);
            acc[4 + i][2 + j] = MFMA_BF16(af[i][1], b1[j][1], acc[4 + i][2 + j]);
        }
    __builtin_amdgcn_s_setprio(0);
    BARRIER();

    // ---- phase 4: Q(1,0) -- no reads (b0/af regs live); stage kt2.A0
    //      (all A reads of cur finished in p3); counted-vmcnt checkpoint
    if (PF2) stage_half(gA, sAc, 0, kt2, K, tid);
    BARRIER();
    __builtin_amdgcn_s_setprio(1);
#pragma unroll
    for (int i = 0; i < 4; ++i)
#pragma unroll
        for (int j = 0; j < 2; ++j) {
            acc[4 + i][j] = MFMA_BF16(af[i][0], b0[j][0], acc[4 + i][j]);
            acc[4 + i][j] = MFMA_BF16(af[i][1], b0[j][1], acc[4 + i][j]);
        }
    __builtin_amdgcn_s_setprio(0);
    if (CKPT == 4)      asm volatile("s_waitcnt vmcnt(4)");
    else if (CKPT == 0) asm volatile("s_waitcnt vmcnt(0)");
    BARRIER();
}

// ---------------------------------------------------------------------------
// GEMM: C[e] = relu(A[e] @ Bt[e]^T + bias[e]) ; bf16 in, fp32 acc, bf16 out
// A: [M,K] rm, Bt: [N,K] rm, C: [M,N] rm. tile 256x256, BK=64, NT = K/64
// (even, >=4 for all layers). grid = (M/256, N/256, 8), all pow2, total%8==0.
// ---------------------------------------------------------------------------
__global__ __launch_bounds__(512, 2) void gemm256_bias_relu_kernel(
    const unsigned short* __restrict__ A, long long Aes,
    const unsigned short* __restrict__ Bt, long long Bes,
    const float* __restrict__ bias, long long bias_es,
    unsigned short* __restrict__ C, long long Ces,
    int M, int N, int K) {
    __shared__ __align__(16) unsigned short sA[2][16384];  // [buf][256*64]
    __shared__ __align__(16) unsigned short sB[2][16384];

    const int tid  = threadIdx.x;
    const int lane = tid & 63;
    const int w    = tid >> 6;        // wave 0..7
    const int wm   = w >> 2;          // 0..1  (M half)
    const int wn   = w & 3;           // 0..3  (N quarter)
    const int quad = lane >> 4, l15 = lane & 15;
    const int swz  = l15 & 7;
    const int srow = tid >> 3;        // staging row 0..63
    const int schk = tid & 7;         // staging 16B chunk
    const int gchunk = schk ^ (srow & 7);   // source pre-swizzle

    // XCD-ownership block swizzle (lin%8 -> XCD heuristic)
    const unsigned int gy   = gridDim.y;
    const unsigned int lin  = blockIdx.x + gridDim.x * (blockIdx.y + gy * blockIdx.z);
    const unsigned int e    = lin & 7;
    const unsigned int slot = lin >> 3;
    const int gysh = __builtin_ctz(gy);
    const int n0 = (int)(slot & (gy - 1)) * 256;   // n fastest within XCD
    const int m0 = (int)(slot >> gysh) * 256;

    A    += (size_t)e * Aes;
    Bt   += (size_t)e * Bes;
    bias += (size_t)e * bias_es;
    C    += (size_t)e * Ces;

    const unsigned short* gA = A  + (size_t)(m0 + srow) * K + gchunk * 8;
    const unsigned short* gB = Bt + (size_t)(n0 + srow) * K + gchunk * 8;

    f32x4 acc[8][4] = {};

    // prologue: T0 {B0,A0,B1,A1} -> buf0 ; T1 {B0,A0} -> buf1 ; vmcnt(4)
    stage_half(gB, sB[0], 0, 0, K, tid);
    stage_half(gA, sA[0], 0, 0, K, tid);
    stage_half(gB, sB[0], 1, 0, K, tid);
    stage_half(gA, sA[0], 1, 0, K, tid);
    stage_half(gB, sB[1], 0, 1, K, tid);
    stage_half(gA, sA[1], 0, 1, K, tid);
    asm volatile("s_waitcnt vmcnt(4)");
    BARRIER();

    const int aRow = (wm * 128 + l15) * 64;
    const int bRow = (wn * 64 + l15) * 64;
    const int ck0  = ((0 + quad) ^ swz) * 8;    // k-slice 0 chunk (swizzled)
    const int ck1  = ((4 + quad) ^ swz) * 8;    // k-slice 1 chunk
    const int NT   = K >> 6;

    int t = 0;
    for (; t + 3 < NT; t += 2) {
        tile8<true, true, 4>(sA[0], sB[0], sA[1], sB[1], gA, gB, K, tid,
                             aRow, bRow, ck0, ck1, t + 1, t + 2, acc);
        tile8<true, true, 4>(sA[1], sB[1], sA[0], sB[0], gA, gB, K, tid,
                             aRow, bRow, ck0, ck1, t + 2, t + 3, acc);
    }
    // t == NT-2: finish staging T(NT-1), drain, then last tile w/o prefetch
    tile8<true, false, 0>(sA[0], sB[0], sA[1], sB[1], gA, gB, K, tid,
                          aRow, bRow, ck0, ck1, NT - 1, 0, acc);
    tile8<false, false, -1>(sA[1], sB[1], sA[0], sB[0], gA, gB, K, tid,
                            aRow, bRow, ck0, ck1, 0, 0, acc);

    // epilogue: C/D layout col=lane&15, row=quad*4+reg.
    // row-outer / j-inner: each wave completes each 128B C-line in 4
    // consecutive stores.
    float bv[4];
#pragma unroll
    for (int j = 0; j < 4; ++j) bv[j] = bias[n0 + wn * 64 + j * 16 + l15];
#pragma unroll
    for (int i = 0; i < 8; ++i) {
#pragma unroll
        for (int r = 0; r < 4; ++r) {
            const int row = m0 + wm * 128 + i * 16 + quad * 4 + r;
            unsigned short* Crow = &C[(size_t)row * N + n0 + wn * 64 + l15];
#pragma unroll
            for (int j = 0; j < 4; ++j) {
                float v = acc[i][j][r] + bv[j];
                v = v > 0.f ? v : 0.f;
                Crow[j * 16] = f2bf(v);
            }
        }
    }
}

// ---------------------------------------------------------------------------
// gates + x->bf16 convert fused. block 256 = 8 rows x 32 outputs.
// ---------------------------------------------------------------------------
__global__ void gates_convert_kernel(const float* __restrict__ x,
                                     const float* __restrict__ gw,
                                     float* __restrict__ gates,
                                     unsigned short* __restrict__ xb) {
    const int tid = threadIdx.x;
    const size_t base = (size_t)blockIdx.x * 8192 + (size_t)tid * 32;
#pragma unroll
    for (int i = 0; i < 8; ++i) {
        float4 v = *(const float4*)&x[base + i * 4];
        us4 o4;
        o4.x = f2bf(v.x); o4.y = f2bf(v.y); o4.z = f2bf(v.z); o4.w = f2bf(v.w);
        ((us4*)xb)[base / 4 + i] = o4;
    }
    const int o = tid & 31;          // t*8 + e
    const int r = tid >> 5;          // 0..7
    const int b = blockIdx.x * 8 + r;
    const float* xr = x + (size_t)b * D_IN;
    float acc = 0.f;
    for (int k = 0; k < D_IN; k += 4) {
        float4 xv = *(const float4*)&xr[k];
        acc += xv.x * gw[(k + 0) * 32 + o];
        acc += xv.y * gw[(k + 1) * 32 + o];
        acc += xv.z * gw[(k + 2) * 32 + o];
        acc += xv.w * gw[(k + 3) * 32 + o];
    }
    float m = acc;
    m = fmaxf(m, __shfl_xor(m, 1));
    m = fmaxf(m, __shfl_xor(m, 2));
    m = fmaxf(m, __shfl_xor(m, 4));
    float ex = __expf(acc - m);
    float s = ex;
    s += __shfl_xor(s, 1);
    s += __shfl_xor(s, 2);
    s += __shfl_xor(s, 4);
    gates[(size_t)b * 32 + o] = ex / s;
}

// ---------------------------------------------------------------------------
// combine: out[t][b][d] = sum_e h3[e][b][d] * g[b][t*8+e]
// ---------------------------------------------------------------------------
__global__ void combine_kernel(const unsigned short* __restrict__ h3,
                               const float* __restrict__ gates,
                               float* __restrict__ out) {
    __shared__ float g[32];
    const int b = blockIdx.x;
    const int d = threadIdx.x;
    if (d < 32) g[d] = gates[(size_t)b * 32 + d];
    __syncthreads();
    float acc[NTASK] = {0.f, 0.f, 0.f, 0.f};
#pragma unroll
    for (int e = 0; e < NEXP; ++e) {
        const float h = bf2f(h3[((size_t)e * B_ROWS + b) * H3 + d]);
#pragma unroll
        for (int t = 0; t < NTASK; ++t) acc[t] += h * g[t * 8 + e];
    }
#pragma unroll
    for (int t = 0; t < NTASK; ++t)
        out[((size_t)t * B_ROWS + b) * H3 + d] = acc[t];
}

// ---------------------------------------------------------------------------
// workspace layout (bytes)
// ---------------------------------------------------------------------------
#define OFF_XBF 0u                          // 8192*1024*2      = 16,777,216
#define OFF_W1T 16777216u                   // 8*1024*1024*2    = 16,777,216
#define OFF_W2T 33554432u                   // 8*512*1024*2     =  8,388,608
#define OFF_W3T 41943040u                   // 8*256*512*2      =  2,097,152
#define OFF_G   44040192u                   // 8192*32*4        =  1,048,576
#define OFF_H1  45088768u                   // 8*8192*1024*2    = 134,217,728
#define OFF_H2  179306496u                  // 8*8192*512*2     = 67,108,864
#define OFF_H3  45088768u                   // aliases h1 (h1 dead after L2)
// total required: 246,415,360 bytes

extern "C" void kernel_launch(void* const* d_in, const int* in_sizes, int n_in,
                              void* d_out, int out_size, void* d_ws, size_t ws_size,
                              hipStream_t stream) {
    const float* x  = (const float*)d_in[0];
    const float* W1 = (const float*)d_in[1];
    const float* b1 = (const float*)d_in[2];
    const float* W2 = (const float*)d_in[3];
    const float* b2 = (const float*)d_in[4];
    const float* W3 = (const float*)d_in[5];
    const float* b3 = (const float*)d_in[6];
    const float* gw = (const float*)d_in[7];
    float* out = (float*)d_out;
    char* ws = (char*)d_ws;

    unsigned short* xbf = (unsigned short*)(ws + OFF_XBF);
    unsigned short* w1t = (unsigned short*)(ws + OFF_W1T);
    unsigned short* w2t = (unsigned short*)(ws + OFF_W2T);
    unsigned short* w3t = (unsigned short*)(ws + OFF_W3T);
    float*          gts = (float*)(ws + OFF_G);
    unsigned short* h1  = (unsigned short*)(ws + OFF_H1);
    unsigned short* h2  = (unsigned short*)(ws + OFF_H2);
    unsigned short* h3  = (unsigned short*)(ws + OFF_H3);

    // weight transposes + fused gates/x-convert
    transpose_convert_kernel<<<dim3(D_IN / 64, H1 / 64, NEXP), dim3(256), 0, stream>>>(W1, w1t, D_IN, H1);
    transpose_convert_kernel<<<dim3(H1 / 64, H2 / 64, NEXP), dim3(256), 0, stream>>>(W2, w2t, H1, H2);
    transpose_convert_kernel<<<dim3(H2 / 64, H3 / 64, NEXP), dim3(256), 0, stream>>>(W3, w3t, H2, H3);
    gates_convert_kernel<<<dim3(B_ROWS / 8), dim3(256), 0, stream>>>(x, gw, gts, xbf);

    // expert MLP layers (256x256 8-phase GEMM)
    gemm256_bias_relu_kernel<<<dim3(B_ROWS / 256, H1 / 256, NEXP), dim3(512), 0, stream>>>(
        xbf, 0LL,
        w1t, (long long)H1 * D_IN,
        b1, (long long)H1,
        h1, (long long)B_ROWS * H1,
        B_ROWS, H1, D_IN);
    gemm256_bias_relu_kernel<<<dim3(B_ROWS / 256, H2 / 256, NEXP), dim3(512), 0, stream>>>(
        h1, (long long)B_ROWS * H1,
        w2t, (long long)H2 * H1,
        b2, (long long)H2,
        h2, (long long)B_ROWS * H2,
        B_ROWS, H2, H1);
    gemm256_bias_relu_kernel<<<dim3(B_ROWS / 256, H3 / 256, NEXP), dim3(512), 0, stream>>>(
        h2, (long long)B_ROWS * H2,
        w3t, (long long)H3 * H2,
        b3, (long long)H3,
        h3, (long long)B_ROWS * H3,
        B_ROWS, H3, H2);

    // gated combine
    combine_kernel<<<dim3(B_ROWS), dim3(256), 0, stream>>>(h3, gts, out);
}

// Round 5
// 465.887 us; speedup vs baseline: 1.2617x; 1.2096x over previous
//
#include <hip/hip_runtime.h>

// ---------------------------------------------------------------------------
// MMoE: B=8192, D_IN=1024, E=8, T=4, H1=1024, H2=512, H3=256
// R12: REVERT to the R7 structure (8-phase family abandoned: R8/R9/R10 all
// plateaued at 25-29% MfmaUtil -- this toolchain forces a vmcnt drain at
// every s_barrier with outstanding global_load_lds, so the counted-vmcnt
// pipeline is unreachable from HIP source here; R7's 4-blocks/CU wave
// overlap absorbs the drain better).
// One change vs R7: MFMA shape 16x16x32 -> 32x32x16 (same FLOPs, same LDS
// bytes, ~20% faster pipe per m06/m119, half the MFMA issue slots ->
// relieves the shared-SIMD issue pressure behind VALUBusy=33%).
//   per wave: 64x64 = 2x2 of 32x32, acc = 4 x f32x16 (64 VGPR, unchanged)
//   fragment: A[row=l&31][k=(l>>5)*8+r]; C/D col=lane&31,
//             row=(reg&3)+8*(reg>>2)+4*(lane>>5)  (m74/m101-verified)
//   swizzled read chunk = (s*2+h)^(l31&7), same staging involution as R7.
// Rest identical to R7: tile 128x128, BK=64, launch_bounds(256,4),
// XCD-ownership block swizzle (e=lin&7, n fastest), vectorized weight
// transpose, fused gates/x-convert, fused bias+relu epilogues.
// ---------------------------------------------------------------------------

#define B_ROWS 8192
#define D_IN   1024
#define NEXP   8
#define NTASK  4
#define H1     1024
#define H2     512
#define H3     256

typedef __attribute__((ext_vector_type(8))) short bf16x8;
typedef __attribute__((ext_vector_type(16))) float f32x16;

__device__ __forceinline__ unsigned short f2bf(float f) {
    union { float f; unsigned int u; } x; x.f = f;
    unsigned int r = x.u + 0x7fffu + ((x.u >> 16) & 1u);  // RNE
    return (unsigned short)(r >> 16);
}
__device__ __forceinline__ float bf2f(unsigned short u) {
    union { unsigned int u; float f; } x; x.u = ((unsigned int)u) << 16;
    return x.f;
}

__device__ __forceinline__ void gload_lds16(const void* gptr, void* lptr) {
    __builtin_amdgcn_global_load_lds(
        (__attribute__((address_space(1))) void*)gptr,
        (__attribute__((address_space(3))) void*)lptr,
        16, 0, 0);
}

struct __align__(8) us4 { unsigned short x, y, z, w; };

// ---------------------------------------------------------------------------
// W [E][K][N] fp32 -> Wt [E][N][K] bf16. 64x64 tiles, block 256.
// Reads coalesced dwords; writes 8B us4 (16 threads x 8B = 128B/row-segment).
// LDS: 65-float row stride -> write-side reads are 2-way (free).
// ---------------------------------------------------------------------------
__global__ void transpose_convert_kernel(const float* __restrict__ W,
                                         unsigned short* __restrict__ Wt,
                                         int K, int N) {
    __shared__ float tile[64][65];
    const int e = blockIdx.z;
    const float* We = W + (size_t)e * K * N;
    unsigned short* Wte = Wt + (size_t)e * K * N;
    const int k0 = blockIdx.x * 64, n0 = blockIdx.y * 64;
    const int tid = threadIdx.x;
    const int tn = tid & 63;             // n within tile (read side)
    const int tk = tid >> 6;             // 0..3
#pragma unroll
    for (int i = 0; i < 16; ++i)
        tile[tk * 16 + i][tn] = We[(size_t)(k0 + tk * 16 + i) * N + n0 + tn];
    __syncthreads();
    const int wk = (tid & 15) * 4;       // k-chunk start (write side)
    const int wn = tid >> 4;             // 0..15
#pragma unroll
    for (int i = 0; i < 4; ++i) {
        const int n = wn + i * 16;
        us4 o;
        o.x = f2bf(tile[wk + 0][n]);
        o.y = f2bf(tile[wk + 1][n]);
        o.z = f2bf(tile[wk + 2][n]);
        o.w = f2bf(tile[wk + 3][n]);
        *(us4*)&Wte[(size_t)(n0 + n) * K + k0 + wk] = o;
    }
}

// ---------------------------------------------------------------------------
// GEMM: C[e] = relu(A[e] @ Bt[e]^T + bias[e]) ; all bf16, acc fp32
// A: [M,K] rm (per-expert stride Aes elems), Bt: [N,K] rm, C: [M,N] rm bf16
// block = 256 (4 waves, 2x2), tile 128x128, BK=64, single-buffered.
// XOR-swizzled LDS (chunk c of row r holds global chunk c^(r&7)): 0 conflicts.
// MFMA 32x32x16: per wave 2x2 acc of f32x16.
// XCD-ownership swizzle: e = lin&7, slot = lin>>3; n = slot & (gy-1),
// m = slot >> log2(gy). Requires gridDim = (M/128, N/128, 8), all pow2.
// launch_bounds(256,4): 4 blocks/CU, 16 waves/CU.
// ---------------------------------------------------------------------------
__global__ __launch_bounds__(256, 4) void gemm_bias_relu_kernel(
    const unsigned short* __restrict__ A, long long Aes,
    const unsigned short* __restrict__ Bt, long long Bes,
    const float* __restrict__ bias, long long bias_es,
    unsigned short* __restrict__ C, long long Ces,
    int M, int N, int K) {
    __shared__ __align__(16) unsigned short sA[128 * 64];
    __shared__ __align__(16) unsigned short sB[128 * 64];

    const int tid  = threadIdx.x;
    const int lane = tid & 63;
    const int w    = tid >> 6;       // wave 0..3
    const int wr   = w >> 1, wc = w & 1;
    const int l31  = lane & 31;      // row/col within 32x32 tile
    const int h    = lane >> 5;      // k-half selector
    const int swz8 = l31 & 7;        // read-side XOR (row&7 of fragment rows)
    const int r8   = lane >> 3;      // staging row-in-octet 0..7
    const int c8   = lane & 7;       // staging 16B-chunk 0..7
    const int gchunk = c8 ^ r8;      // XOR-swizzled global chunk to fetch

    // XCD-ownership block swizzle
    const unsigned int gy   = gridDim.y;
    const unsigned int lin  = blockIdx.x + gridDim.x * (blockIdx.y + gy * blockIdx.z);
    const unsigned int e    = lin & 7;              // heuristic: lin%8 -> XCD
    const unsigned int slot = lin >> 3;
    const int gysh = __builtin_ctz(gy);
    const int n0 = (int)(slot & (gy - 1)) * 128;    // n fastest within XCD
    const int m0 = (int)(slot >> gysh) * 128;       // m outer

    A    += (size_t)e * Aes;
    Bt   += (size_t)e * Bes;
    bias += (size_t)e * bias_es;
    C    += (size_t)e * Ces;

    // staging: wave w covers A rows [w*32,w*32+32) and B rows [w*32,w*32+32)
    const unsigned short* Abase = A + (size_t)(m0 + w * 32 + r8) * K + gchunk * 8;
    const unsigned short* Bbase = Bt + (size_t)(n0 + w * 32 + r8) * K + gchunk * 8;
    unsigned short* sAw = &sA[(w * 32 + r8) * 64 + c8 * 8];
    unsigned short* sBw = &sB[(w * 32 + r8) * 64 + c8 * 8];

    f32x16 acc[2][2] = {};

    for (int k0 = 0; k0 < K; k0 += 64) {
#pragma unroll
        for (int q = 0; q < 4; ++q) {
            gload_lds16(Abase + (size_t)(q * 8) * K + k0, sAw + q * 8 * 64);
            gload_lds16(Bbase + (size_t)(q * 8) * K + k0, sBw + q * 8 * 64);
        }
        __syncthreads();

#pragma unroll
        for (int s = 0; s < 4; ++s) {
            // global k-chunk (s*2+h) of each fragment row, swizzle-corrected
            const int cs = ((s * 2 + h) ^ swz8) * 8;
            bf16x8 af[2], bfv[2];
#pragma unroll
            for (int i = 0; i < 2; ++i)
                af[i] = *(const bf16x8*)&sA[(wr * 64 + i * 32 + l31) * 64 + cs];
#pragma unroll
            for (int j = 0; j < 2; ++j)
                bfv[j] = *(const bf16x8*)&sB[(wc * 64 + j * 32 + l31) * 64 + cs];
#pragma unroll
            for (int i = 0; i < 2; ++i)
#pragma unroll
                for (int j = 0; j < 2; ++j)
                    acc[i][j] = __builtin_amdgcn_mfma_f32_32x32x16_bf16(
                        af[i], bfv[j], acc[i][j], 0, 0, 0);
        }
        __syncthreads();
    }

    // epilogue: 32x32 C/D layout col=lane&31, row=(r&3)+8*(r>>2)+4*h
    float bvj[2];
#pragma unroll
    for (int j = 0; j < 2; ++j) bvj[j] = bias[n0 + wc * 64 + j * 32 + l31];
#pragma unroll
    for (int i = 0; i < 2; ++i) {
#pragma unroll
        for (int j = 0; j < 2; ++j) {
            const int col = n0 + wc * 64 + j * 32 + l31;
#pragma unroll
            for (int r = 0; r < 16; ++r) {
                const int row = m0 + wr * 64 + i * 32 + (r & 3) + 8 * (r >> 2) + 4 * h;
                float v = acc[i][j][r] + bvj[j];
                v = v > 0.f ? v : 0.f;
                C[(size_t)row * N + col] = f2bf(v);
            }
        }
    }
}

// ---------------------------------------------------------------------------
// gates + x->bf16 convert fused.
// block 256 = 8 rows x 32 outputs; also converts this block's 8 x-rows.
// ---------------------------------------------------------------------------
__global__ void gates_convert_kernel(const float* __restrict__ x,
                                     const float* __restrict__ gw,
                                     float* __restrict__ gates,
                                     unsigned short* __restrict__ xb) {
    const int tid = threadIdx.x;
    const size_t base = (size_t)blockIdx.x * 8192 + (size_t)tid * 32;
#pragma unroll
    for (int i = 0; i < 8; ++i) {
        float4 v = *(const float4*)&x[base + i * 4];
        us4 o4;
        o4.x = f2bf(v.x); o4.y = f2bf(v.y); o4.z = f2bf(v.z); o4.w = f2bf(v.w);
        ((us4*)xb)[base / 4 + i] = o4;
    }
    const int o = tid & 31;          // t*8 + e
    const int r = tid >> 5;          // 0..7
    const int b = blockIdx.x * 8 + r;
    const float* xr = x + (size_t)b * D_IN;
    float acc = 0.f;
    for (int k = 0; k < D_IN; k += 4) {
        float4 xv = *(const float4*)&xr[k];
        acc += xv.x * gw[(k + 0) * 32 + o];
        acc += xv.y * gw[(k + 1) * 32 + o];
        acc += xv.z * gw[(k + 2) * 32 + o];
        acc += xv.w * gw[(k + 3) * 32 + o];
    }
    float m = acc;
    m = fmaxf(m, __shfl_xor(m, 1));
    m = fmaxf(m, __shfl_xor(m, 2));
    m = fmaxf(m, __shfl_xor(m, 4));
    float ex = __expf(acc - m);
    float s = ex;
    s += __shfl_xor(s, 1);
    s += __shfl_xor(s, 2);
    s += __shfl_xor(s, 4);
    gates[(size_t)b * 32 + o] = ex / s;
}

// ---------------------------------------------------------------------------
// combine: out[t][b][d] = sum_e h3[e][b][d] * g[b][t*8+e]
// ---------------------------------------------------------------------------
__global__ void combine_kernel(const unsigned short* __restrict__ h3,
                               const float* __restrict__ gates,
                               float* __restrict__ out) {
    __shared__ float g[32];
    const int b = blockIdx.x;
    const int d = threadIdx.x;
    if (d < 32) g[d] = gates[(size_t)b * 32 + d];
    __syncthreads();
    float acc[NTASK] = {0.f, 0.f, 0.f, 0.f};
#pragma unroll
    for (int e = 0; e < NEXP; ++e) {
        const float h = bf2f(h3[((size_t)e * B_ROWS + b) * H3 + d]);
#pragma unroll
        for (int t = 0; t < NTASK; ++t) acc[t] += h * g[t * 8 + e];
    }
#pragma unroll
    for (int t = 0; t < NTASK; ++t)
        out[((size_t)t * B_ROWS + b) * H3 + d] = acc[t];
}

// ---------------------------------------------------------------------------
// workspace layout (bytes)
// ---------------------------------------------------------------------------
#define OFF_XBF 0u                          // 8192*1024*2      = 16,777,216
#define OFF_W1T 16777216u                   // 8*1024*1024*2    = 16,777,216
#define OFF_W2T 33554432u                   // 8*512*1024*2     =  8,388,608
#define OFF_W3T 41943040u                   // 8*256*512*2      =  2,097,152
#define OFF_G   44040192u                   // 8192*32*4        =  1,048,576
#define OFF_H1  45088768u                   // 8*8192*1024*2    = 134,217,728
#define OFF_H2  179306496u                  // 8*8192*512*2     = 67,108,864
#define OFF_H3  45088768u                   // aliases h1 (h1 dead after L2)
// total required: 246,415,360 bytes

extern "C" void kernel_launch(void* const* d_in, const int* in_sizes, int n_in,
                              void* d_out, int out_size, void* d_ws, size_t ws_size,
                              hipStream_t stream) {
    const float* x  = (const float*)d_in[0];
    const float* W1 = (const float*)d_in[1];
    const float* b1 = (const float*)d_in[2];
    const float* W2 = (const float*)d_in[3];
    const float* b2 = (const float*)d_in[4];
    const float* W3 = (const float*)d_in[5];
    const float* b3 = (const float*)d_in[6];
    const float* gw = (const float*)d_in[7];
    float* out = (float*)d_out;
    char* ws = (char*)d_ws;

    unsigned short* xbf = (unsigned short*)(ws + OFF_XBF);
    unsigned short* w1t = (unsigned short*)(ws + OFF_W1T);
    unsigned short* w2t = (unsigned short*)(ws + OFF_W2T);
    unsigned short* w3t = (unsigned short*)(ws + OFF_W3T);
    float*          gts = (float*)(ws + OFF_G);
    unsigned short* h1  = (unsigned short*)(ws + OFF_H1);
    unsigned short* h2  = (unsigned short*)(ws + OFF_H2);
    unsigned short* h3  = (unsigned short*)(ws + OFF_H3);

    // weight transposes + fused gates/x-convert
    transpose_convert_kernel<<<dim3(D_IN / 64, H1 / 64, NEXP), dim3(256), 0, stream>>>(W1, w1t, D_IN, H1);
    transpose_convert_kernel<<<dim3(H1 / 64, H2 / 64, NEXP), dim3(256), 0, stream>>>(W2, w2t, H1, H2);
    transpose_convert_kernel<<<dim3(H2 / 64, H3 / 64, NEXP), dim3(256), 0, stream>>>(W3, w3t, H2, H3);
    gates_convert_kernel<<<dim3(B_ROWS / 8), dim3(256), 0, stream>>>(x, gw, gts, xbf);

    // expert MLP layers
    gemm_bias_relu_kernel<<<dim3(B_ROWS / 128, H1 / 128, NEXP), dim3(256), 0, stream>>>(
        xbf, 0LL,
        w1t, (long long)H1 * D_IN,
        b1, (long long)H1,
        h1, (long long)B_ROWS * H1,
        B_ROWS, H1, D_IN);
    gemm_bias_relu_kernel<<<dim3(B_ROWS / 128, H2 / 128, NEXP), dim3(256), 0, stream>>>(
        h1, (long long)B_ROWS * H1,
        w2t, (long long)H2 * H1,
        b2, (long long)H2,
        h2, (long long)B_ROWS * H2,
        B_ROWS, H2, H1);
    gemm_bias_relu_kernel<<<dim3(B_ROWS / 128, H3 / 128, NEXP), dim3(256), 0, stream>>>(
        h2, (long long)B_ROWS * H2,
        w3t, (long long)H3 * H2,
        b3, (long long)H3,
        h3, (long long)B_ROWS * H3,
        B_ROWS, H3, H2);

    // gated combine
    combine_kernel<<<dim3(B_ROWS), dim3(256), 0, stream>>>(h3, gts, out);
}

// Round 6
// 427.128 us; speedup vs baseline: 1.3762x; 1.0907x over previous
//
#include <hip/hip_runtime.h>

// ---------------------------------------------------------------------------
// MMoE: B=8192, D_IN=1024, E=8, T=4, H1=1024, H2=512, H3=256
// R13: GEMM core = exact R7 revert (16x16x32 mfma, 128x128 tile, BK=64,
// XOR-swizzled LDS, launch_bounds(256,4), XCD-ownership swizzle).
//   - R12 (32x32x16) regressed: fragment read shares bank-groups among lanes
//     {k,k+8,k+16,k+24} -> 16.78M conflict-cycles = exactly the +26us.
//     16x16 quad-in-chunk pattern measures 0 conflicts. 32x32 closed.
//   - 8-phase family closed (R8-R11: toolchain drains vmcnt at s_barrier).
// One new change: 3 transpose launches + gates launch merged into ONE
// prep_kernel (flat grid, gates blocks first so xbf is ready earliest).
// Saves 3 launch overheads + tail packing; zero risk to GEMM core.
// ---------------------------------------------------------------------------

#define B_ROWS 8192
#define D_IN   1024
#define NEXP   8
#define NTASK  4
#define H1     1024
#define H2     512
#define H3     256

typedef __attribute__((ext_vector_type(8))) short bf16x8;
typedef __attribute__((ext_vector_type(4))) float f32x4;

__device__ __forceinline__ unsigned short f2bf(float f) {
    union { float f; unsigned int u; } x; x.f = f;
    unsigned int r = x.u + 0x7fffu + ((x.u >> 16) & 1u);  // RNE
    return (unsigned short)(r >> 16);
}
__device__ __forceinline__ float bf2f(unsigned short u) {
    union { unsigned int u; float f; } x; x.u = ((unsigned int)u) << 16;
    return x.f;
}

__device__ __forceinline__ void gload_lds16(const void* gptr, void* lptr) {
    __builtin_amdgcn_global_load_lds(
        (__attribute__((address_space(1))) void*)gptr,
        (__attribute__((address_space(3))) void*)lptr,
        16, 0, 0);
}

struct __align__(8) us4 { unsigned short x, y, z, w; };

// ---------------------------------------------------------------------------
// prep kernel: one launch does gates+x-convert AND all three weight
// transposes (W [E][K][N] fp32 -> Wt [E][N][K] bf16, 64x64 tiles).
// Flat grid partition (256 threads/block):
//   [0,1024)            gates + x->bf16 convert   (1024 blocks)
//   [1024,3072)         W1 transpose (K=1024,N=1024: 256 blk/expert x 8)
//   [3072,4096)         W2 transpose (K=1024,N=512: 128 blk/expert x 8)
//   [4096,4352)         W3 transpose (K=512, N=256:  32 blk/expert x 8)
// ---------------------------------------------------------------------------
__device__ __forceinline__ void transpose_body(
    unsigned int local, const float* __restrict__ W,
    unsigned short* __restrict__ Wt, int K, int N, float (*tile)[65]) {
    const int kt = K >> 6, nt = N >> 6;       // tiles per dim
    const int bpe = kt * nt;                  // blocks per expert
    const int e  = (int)(local / (unsigned)bpe);
    const int rem = (int)(local % (unsigned)bpe);
    const int k0 = (rem % kt) * 64, n0 = (rem / kt) * 64;
    const float* We = W + (size_t)e * K * N;
    unsigned short* Wte = Wt + (size_t)e * K * N;
    const int tid = threadIdx.x;
    const int tn = tid & 63;             // n within tile (read side)
    const int tk = tid >> 6;             // 0..3
#pragma unroll
    for (int i = 0; i < 16; ++i)
        tile[tk * 16 + i][tn] = We[(size_t)(k0 + tk * 16 + i) * N + n0 + tn];
    __syncthreads();
    const int wk = (tid & 15) * 4;       // k-chunk start (write side)
    const int wn = tid >> 4;             // 0..15
#pragma unroll
    for (int i = 0; i < 4; ++i) {
        const int n = wn + i * 16;
        us4 o;
        o.x = f2bf(tile[wk + 0][n]);
        o.y = f2bf(tile[wk + 1][n]);
        o.z = f2bf(tile[wk + 2][n]);
        o.w = f2bf(tile[wk + 3][n]);
        *(us4*)&Wte[(size_t)(n0 + n) * K + k0 + wk] = o;
    }
}

__global__ void prep_kernel(const float* __restrict__ x,
                            const float* __restrict__ gw,
                            float* __restrict__ gates,
                            unsigned short* __restrict__ xb,
                            const float* __restrict__ W1,
                            unsigned short* __restrict__ w1t,
                            const float* __restrict__ W2,
                            unsigned short* __restrict__ w2t,
                            const float* __restrict__ W3,
                            unsigned short* __restrict__ w3t) {
    __shared__ float tile[64][65];
    const unsigned int bid = blockIdx.x;
    if (bid >= 1024u) {
        if (bid < 3072u)       transpose_body(bid - 1024u, W1, w1t, D_IN, H1, tile);
        else if (bid < 4096u)  transpose_body(bid - 3072u, W2, w2t, H1,   H2, tile);
        else                   transpose_body(bid - 4096u, W3, w3t, H2,   H3, tile);
        return;
    }
    // ---- gates + x->bf16 convert (blocks 0..1023, 8 rows x 32 outputs) ----
    const int tid = threadIdx.x;
    const size_t base = (size_t)bid * 8192 + (size_t)tid * 32;
#pragma unroll
    for (int i = 0; i < 8; ++i) {
        float4 v = *(const float4*)&x[base + i * 4];
        us4 o4;
        o4.x = f2bf(v.x); o4.y = f2bf(v.y); o4.z = f2bf(v.z); o4.w = f2bf(v.w);
        ((us4*)xb)[base / 4 + i] = o4;
    }
    const int o = tid & 31;          // t*8 + e
    const int r = tid >> 5;          // 0..7
    const int b = (int)bid * 8 + r;
    const float* xr = x + (size_t)b * D_IN;
    float acc = 0.f;
    for (int k = 0; k < D_IN; k += 4) {
        float4 xv = *(const float4*)&xr[k];
        acc += xv.x * gw[(k + 0) * 32 + o];
        acc += xv.y * gw[(k + 1) * 32 + o];
        acc += xv.z * gw[(k + 2) * 32 + o];
        acc += xv.w * gw[(k + 3) * 32 + o];
    }
    float m = acc;
    m = fmaxf(m, __shfl_xor(m, 1));
    m = fmaxf(m, __shfl_xor(m, 2));
    m = fmaxf(m, __shfl_xor(m, 4));
    float ex = __expf(acc - m);
    float s = ex;
    s += __shfl_xor(s, 1);
    s += __shfl_xor(s, 2);
    s += __shfl_xor(s, 4);
    gates[(size_t)b * 32 + o] = ex / s;
}

// ---------------------------------------------------------------------------
// GEMM: C[e] = relu(A[e] @ Bt[e]^T + bias[e]) ; all bf16, acc fp32
// A: [M,K] rm (per-expert stride Aes elems), Bt: [N,K] rm, C: [M,N] rm bf16
// block = 256 (4 waves, 2x2), tile 128x128, BK=64, single-buffered.
// XOR-swizzled LDS (chunk c of row r holds global chunk c^(r&7)): 0 conflicts.
// XCD-ownership swizzle: e = lin&7, slot = lin>>3; n = slot & (gy-1),
// m = slot >> log2(gy). Requires gridDim = (M/128, N/128, 8), all pow2.
// launch_bounds(256,4): 4 blocks/CU, 16 waves/CU.
// ---------------------------------------------------------------------------
__global__ __launch_bounds__(256, 4) void gemm_bias_relu_kernel(
    const unsigned short* __restrict__ A, long long Aes,
    const unsigned short* __restrict__ Bt, long long Bes,
    const float* __restrict__ bias, long long bias_es,
    unsigned short* __restrict__ C, long long Ces,
    int M, int N, int K) {
    __shared__ __align__(16) unsigned short sA[128 * 64];
    __shared__ __align__(16) unsigned short sB[128 * 64];

    const int tid  = threadIdx.x;
    const int lane = tid & 63;
    const int w    = tid >> 6;       // wave 0..3
    const int wr   = w >> 1, wc = w & 1;
    const int quad = lane >> 4, l15 = lane & 15;
    const int r8   = lane >> 3;      // staging row-in-octet 0..7
    const int c8   = lane & 7;       // staging 16B-chunk 0..7
    const int gchunk = c8 ^ r8;      // XOR-swizzled global chunk to fetch

    // XCD-ownership block swizzle
    const unsigned int gy   = gridDim.y;
    const unsigned int lin  = blockIdx.x + gridDim.x * (blockIdx.y + gy * blockIdx.z);
    const unsigned int e    = lin & 7;              // heuristic: lin%8 -> XCD
    const unsigned int slot = lin >> 3;
    const int gysh = __builtin_ctz(gy);
    const int n0 = (int)(slot & (gy - 1)) * 128;    // n fastest within XCD
    const int m0 = (int)(slot >> gysh) * 128;       // m outer

    A    += (size_t)e * Aes;
    Bt   += (size_t)e * Bes;
    bias += (size_t)e * bias_es;
    C    += (size_t)e * Ces;

    // staging: wave w covers A rows [w*32,w*32+32) and B rows [w*32,w*32+32)
    const unsigned short* Abase = A + (size_t)(m0 + w * 32 + r8) * K + gchunk * 8;
    const unsigned short* Bbase = Bt + (size_t)(n0 + w * 32 + r8) * K + gchunk * 8;
    unsigned short* sAw = &sA[(w * 32 + r8) * 64 + c8 * 8];
    unsigned short* sBw = &sB[(w * 32 + r8) * 64 + c8 * 8];

    f32x4 acc[4][4] = {};
    const int swz = l15 & 7;         // read-side XOR (row&7 of fragment rows)

    for (int k0 = 0; k0 < K; k0 += 64) {
#pragma unroll
        for (int q = 0; q < 4; ++q) {
            gload_lds16(Abase + (size_t)(q * 8) * K + k0, sAw + q * 8 * 64);
            gload_lds16(Bbase + (size_t)(q * 8) * K + k0, sBw + q * 8 * 64);
        }
        __syncthreads();

#pragma unroll
        for (int s = 0; s < 2; ++s) {
            const int cs = ((s * 4 + quad) ^ swz) * 8;  // swizzled k-chunk
            bf16x8 af[4], bfv[4];
#pragma unroll
            for (int i = 0; i < 4; ++i)
                af[i] = *(const bf16x8*)&sA[(wr * 64 + i * 16 + l15) * 64 + cs];
#pragma unroll
            for (int j = 0; j < 4; ++j)
                bfv[j] = *(const bf16x8*)&sB[(wc * 64 + j * 16 + l15) * 64 + cs];
#pragma unroll
            for (int i = 0; i < 4; ++i)
#pragma unroll
                for (int j = 0; j < 4; ++j)
                    acc[i][j] = __builtin_amdgcn_mfma_f32_16x16x32_bf16(
                        af[i], bfv[j], acc[i][j], 0, 0, 0);
        }
        __syncthreads();
    }

    // epilogue: C/D layout col=lane&15, row=quad*4+reg
#pragma unroll
    for (int j = 0; j < 4; ++j) {
        const int col = n0 + wc * 64 + j * 16 + l15;
        const float bv = bias[col];
#pragma unroll
        for (int i = 0; i < 4; ++i) {
#pragma unroll
            for (int r = 0; r < 4; ++r) {
                const int row = m0 + wr * 64 + i * 16 + quad * 4 + r;
                float v = acc[i][j][r] + bv;
                v = v > 0.f ? v : 0.f;
                C[(size_t)row * N + col] = f2bf(v);
            }
        }
    }
}

// ---------------------------------------------------------------------------
// combine: out[t][b][d] = sum_e h3[e][b][d] * g[b][t*8+e]
// ---------------------------------------------------------------------------
__global__ void combine_kernel(const unsigned short* __restrict__ h3,
                               const float* __restrict__ gates,
                               float* __restrict__ out) {
    __shared__ float g[32];
    const int b = blockIdx.x;
    const int d = threadIdx.x;
    if (d < 32) g[d] = gates[(size_t)b * 32 + d];
    __syncthreads();
    float acc[NTASK] = {0.f, 0.f, 0.f, 0.f};
#pragma unroll
    for (int e = 0; e < NEXP; ++e) {
        const float h = bf2f(h3[((size_t)e * B_ROWS + b) * H3 + d]);
#pragma unroll
        for (int t = 0; t < NTASK; ++t) acc[t] += h * g[t * 8 + e];
    }
#pragma unroll
    for (int t = 0; t < NTASK; ++t)
        out[((size_t)t * B_ROWS + b) * H3 + d] = acc[t];
}

// ---------------------------------------------------------------------------
// workspace layout (bytes)
// ---------------------------------------------------------------------------
#define OFF_XBF 0u                          // 8192*1024*2      = 16,777,216
#define OFF_W1T 16777216u                   // 8*1024*1024*2    = 16,777,216
#define OFF_W2T 33554432u                   // 8*512*1024*2     =  8,388,608
#define OFF_W3T 41943040u                   // 8*256*512*2      =  2,097,152
#define OFF_G   44040192u                   // 8192*32*4        =  1,048,576
#define OFF_H1  45088768u                   // 8*8192*1024*2    = 134,217,728
#define OFF_H2  179306496u                  // 8*8192*512*2     = 67,108,864
#define OFF_H3  45088768u                   // aliases h1 (h1 dead after L2)
// total required: 246,415,360 bytes

extern "C" void kernel_launch(void* const* d_in, const int* in_sizes, int n_in,
                              void* d_out, int out_size, void* d_ws, size_t ws_size,
                              hipStream_t stream) {
    const float* x  = (const float*)d_in[0];
    const float* W1 = (const float*)d_in[1];
    const float* b1 = (const float*)d_in[2];
    const float* W2 = (const float*)d_in[3];
    const float* b2 = (const float*)d_in[4];
    const float* W3 = (const float*)d_in[5];
    const float* b3 = (const float*)d_in[6];
    const float* gw = (const float*)d_in[7];
    float* out = (float*)d_out;
    char* ws = (char*)d_ws;

    unsigned short* xbf = (unsigned short*)(ws + OFF_XBF);
    unsigned short* w1t = (unsigned short*)(ws + OFF_W1T);
    unsigned short* w2t = (unsigned short*)(ws + OFF_W2T);
    unsigned short* w3t = (unsigned short*)(ws + OFF_W3T);
    float*          gts = (float*)(ws + OFF_G);
    unsigned short* h1  = (unsigned short*)(ws + OFF_H1);
    unsigned short* h2  = (unsigned short*)(ws + OFF_H2);
    unsigned short* h3  = (unsigned short*)(ws + OFF_H3);

    // fused prep: gates/x-convert (first 1024 blocks) + all weight transposes
    prep_kernel<<<dim3(4352), dim3(256), 0, stream>>>(
        x, gw, gts, xbf, W1, w1t, W2, w2t, W3, w3t);

    // expert MLP layers
    gemm_bias_relu_kernel<<<dim3(B_ROWS / 128, H1 / 128, NEXP), dim3(256), 0, stream>>>(
        xbf, 0LL,
        w1t, (long long)H1 * D_IN,
        b1, (long long)H1,
        h1, (long long)B_ROWS * H1,
        B_ROWS, H1, D_IN);
    gemm_bias_relu_kernel<<<dim3(B_ROWS / 128, H2 / 128, NEXP), dim3(256), 0, stream>>>(
        h1, (long long)B_ROWS * H1,
        w2t, (long long)H2 * H1,
        b2, (long long)H2,
        h2, (long long)B_ROWS * H2,
        B_ROWS, H2, H1);
    gemm_bias_relu_kernel<<<dim3(B_ROWS / 128, H3 / 128, NEXP), dim3(256), 0, stream>>>(
        h2, (long long)B_ROWS * H2,
        w3t, (long long)H3 * H2,
        b3, (long long)H3,
        h3, (long long)B_ROWS * H3,
        B_ROWS, H3, H2);

    // gated combine
    combine_kernel<<<dim3(B_ROWS), dim3(256), 0, stream>>>(h3, gts, out);
}